// Round 2
// baseline (1115.414 us; speedup 1.0000x reference)
//
#include <hip/hip_runtime.h>

#define SS 512
#define BB 2048
#define DD 128
#define HH 8

// ---- DPP helper (compile-time ctrl) ----
template<int CTRL>
__device__ __forceinline__ float dppf(float old_, float src) {
  return __int_as_float(__builtin_amdgcn_update_dpp(
      __float_as_int(old_), __float_as_int(src), CTRL, 0xF, 0xF, false));
}

// ---------------- weight transpose: conv_w[h][d][k] -> wt[k][d][h] ----------------
__global__ void kw_transpose(const float* __restrict__ w, float* __restrict__ wt) {
  int i = blockIdx.x * blockDim.x + threadIdx.x;
  if (i < 3 * DD * HH) {
    int k = i >> 10;          // / (128*8)
    int d = (i >> 3) & 127;
    int h = i & 7;
    wt[i] = w[h * (DD * 3) + d * 3 + k];
  }
}

// ---------------- conv1d (SAME, k=3, no bias): enc[s][b][h] ----------------
__global__ __launch_bounds__(256) void kconv(const float* __restrict__ x,
                                             const float* __restrict__ wt,
                                             float* __restrict__ enc) {
  const int b = blockIdx.x * 256 + threadIdx.x;
  const int s = blockIdx.y;
  float acc0=0.f,acc1=0.f,acc2=0.f,acc3=0.f,acc4=0.f,acc5=0.f,acc6=0.f,acc7=0.f;

  auto proc = [&](float xe, const float* w8) {
    float4 wa = *(const float4*)(w8);
    float4 wb = *(const float4*)(w8 + 4);
    acc0 = fmaf(xe, wa.x, acc0); acc1 = fmaf(xe, wa.y, acc1);
    acc2 = fmaf(xe, wa.z, acc2); acc3 = fmaf(xe, wa.w, acc3);
    acc4 = fmaf(xe, wb.x, acc4); acc5 = fmaf(xe, wb.y, acc5);
    acc6 = fmaf(xe, wb.z, acc6); acc7 = fmaf(xe, wb.w, acc7);
  };

  #pragma unroll
  for (int k = 0; k < 3; ++k) {
    int sr = s + k - 1;
    if (sr >= 0 && sr < SS) {
      const float* xr = x + ((size_t)sr * BB + b) * DD;
      const float* wk = wt + k * (DD * HH);
      #pragma unroll 4
      for (int d = 0; d < DD; d += 4) {
        float4 xv = *(const float4*)(xr + d);
        const float* wp = wk + d * 8;
        proc(xv.x, wp);
        proc(xv.y, wp + 8);
        proc(xv.z, wp + 16);
        proc(xv.w, wp + 24);
      }
    }
  }
  float4* op = (float4*)(enc + ((size_t)s * BB + b) * HH);
  op[0] = make_float4(acc0, acc1, acc2, acc3);
  op[1] = make_float4(acc4, acc5, acc6, acc7);
}

// ---------------- recurrent QLSTM scan ----------------
// 32 lanes per row: lane = gate*8 + q  (gate: 0=F,1=I,2=G,3=O). 2 rows per wave.
__global__ __launch_bounds__(64) void krec(
    const float* __restrict__ ln_g, const float* __restrict__ ln_b,
    const float* __restrict__ Wf, const float* __restrict__ bf,
    const float* __restrict__ Wi, const float* __restrict__ bi,
    const float* __restrict__ Wg, const float* __restrict__ bg,
    const float* __restrict__ Wo, const float* __restrict__ bo,
    float* __restrict__ out)
{
  const int tid  = threadIdx.x;
  const int sub  = tid & 31;
  const int gate = sub >> 3;
  const int q    = sub & 7;
  const int b    = blockIdx.x * 2 + (tid >> 5);

  const float* Wm = (gate == 0) ? Wf : (gate == 1) ? Wi : (gate == 2) ? Wg : Wo;
  const float* bm = (gate == 0) ? bf : (gate == 1) ? bi : (gate == 2) ? bg : bo;

  // Fold LayerNorm gain/bias into the weights:
  //   theta = rinv*(dot(v, g.*W[q,:]) - mu*sum(g.*W[q,:])) + (bias_q + dot(beta, W[q,:]))
  float wraw[16];
  #pragma unroll
  for (int j = 0; j < 16; ++j) wraw[j] = Wm[q * 16 + j];
  float SWp = 0.f, bb = bm[q];
  #pragma unroll
  for (int j = 0; j < 16; ++j) {
    SWp += wraw[j] * ln_g[j];
    bb  = fmaf(ln_b[j], wraw[j], bb);
  }
  float wx[8], wh[8];
  #pragma unroll
  for (int j = 0; j < 8; ++j) wx[j] = wraw[j] * ln_g[j];
  // h arrives via butterfly in order h[q^k] -> permute weights instead of data
  #pragma unroll
  for (int k = 0; k < 8; ++k) { int src = 8 + (q ^ k); wh[k] = wraw[src] * ln_g[src]; }

  const bool  isG  = (gate == 2);
  const float ymul = isG ? 2.f : 1.f;
  const bool  gb0  = (gate & 1) != 0;
  const bool  gb1  = (gate & 2) != 0;

  float h_own = 0.f, c_own = 0.f;
  float r0=0.f,r1=0.f,r2=0.f,r3=0.f,r4=0.f,r5=0.f,r6=0.f,r7=0.f;

  const float4* pl = (const float4*)out + (size_t)b * 2;   // enc[s=0][b]
  float4 cv0 = pl[0], cv1 = pl[1];
  float* pst = out + (size_t)b * 8 + q;

  for (int s = 0; s < SS; ++s) {
    const float x0=cv0.x, x1=cv0.y, x2=cv0.z, x3=cv0.w;
    const float x4=cv1.x, x5=cv1.y, x6=cv1.z, x7=cv1.w;
    if (s + 1 < SS) {            // prefetch next step's enc (uniform branch)
      pl += BB * 2;
      cv0 = pl[0]; cv1 = pl[1];
    }
    // LayerNorm stats over [x(8), h(8)] (trees for ILP)
    float sv = (((x0+x1)+(x2+x3)) + ((x4+x5)+(x6+x7)))
             + (((r0+r1)+(r2+r3)) + ((r4+r5)+(r6+r7)));
    float qa = fmaf(x0,x0, x1*x1) + fmaf(x2,x2, x3*x3);
    float qb = fmaf(x4,x4, x5*x5) + fmaf(x6,x6, x7*x7);
    float qc = fmaf(r0,r0, r1*r1) + fmaf(r2,r2, r3*r3);
    float qd = fmaf(r4,r4, r5*r5) + fmaf(r6,r6, r7*r7);
    float sq  = (qa + qb) + (qc + qd);
    float mu  = sv * 0.0625f;
    float var = fmaf(-mu, mu, sq * 0.0625f);
    float rinv = __builtin_amdgcn_rsqf(var + 1e-5f);
    // dot(v, W')   (4 independent chains)
    float d0 = fmaf(x0,wx[0], x1*wx[1]); d0 = fmaf(x2,wx[2], d0); d0 = fmaf(x3,wx[3], d0);
    float d1 = fmaf(x4,wx[4], x5*wx[5]); d1 = fmaf(x6,wx[6], d1); d1 = fmaf(x7,wx[7], d1);
    float d2 = fmaf(r0,wh[0], r1*wh[1]); d2 = fmaf(r2,wh[2], d2); d2 = fmaf(r3,wh[3], d2);
    float d3 = fmaf(r4,wh[4], r5*wh[5]); d3 = fmaf(r6,wh[6], d3); d3 = fmaf(r7,wh[7], d3);
    float dot = (d0 + d1) + (d2 + d3);
    float theta = fmaf(fmaf(-mu, SWp, dot), rinv, bb);
    float c = __cosf(theta);
    // _qexp: Kogge-Stone cumprod over q of c' (c with q0 -> 1), all DPP
    float cp = (q == 0) ? 1.f : c;
    float t;
    t = dppf<0x111>(cp, cp); cp = (q >= 1) ? cp * t : cp;   // row_shr:1
    t = dppf<0x112>(cp, cp); cp = (q >= 2) ? cp * t : cp;   // row_shr:2
    t = dppf<0x114>(cp, cp); cp = (q >= 4) ? cp * t : cp;   // row_shr:4
    float cb  = dppf<0x00>(c, c);                           // quad_perm(0,0,0,0)
    float cb2 = dppf<0x114>(cb, cb);                        // row_shr:4
    float c0b = (q >= 4) ? cb2 : cb;                        // broadcast c[q=0] in 8-group
    float tot = dppf<0x141>(cp, cp);                        // half_mirror: q0 <- cp[7]
    float outq = (q == 0) ? tot : c0b * cp;
    // activation: sigmoid for F/I/O, tanh for G (tanh(x)=2*sig(2x)-1)
    float e  = __expf(-(outq * ymul));
    float sg = __builtin_amdgcn_rcpf(1.f + e);
    float a  = isG ? fmaf(2.f, sg, -1.f) : sg;
    // gather all four gates' value for this q
    float t1 = dppf<0x128>(a, a);          // row_ror:8 => gate^1
    float t2 = __shfl_xor(a, 16);          // gate^2
    float t3 = __shfl_xor(t1, 16);         // gate^3
    float v01  = gb0 ? t1 : a;
    float v23  = gb0 ? t3 : t2;
    float v01i = gb0 ? a  : t1;
    float v23i = gb0 ? t2 : t3;
    float fv = gb1 ? v23  : v01;
    float gv = gb1 ? v01  : v23;
    float iv = gb1 ? v23i : v01i;
    float ov = gb1 ? v01i : v23i;
    // state update
    c_own = fmaf(fv, c_own, iv * gv);
    float e2 = __expf(-2.f * c_own);
    float th = fmaf(2.f, __builtin_amdgcn_rcpf(1.f + e2), -1.f);
    h_own = ov * th;
    if (gate == 0) *pst = h_own;
    pst += BB * HH;
    // butterfly all-gather of h within the 8-lane q-group: r[k] = h[q^k]
    r0 = h_own;
    r1 = dppf<0xB1>(r0, r0);               // quad_perm(1,0,3,2): ^1
    r2 = dppf<0x4E>(r0, r0);               // quad_perm(2,3,0,1): ^2
    r3 = dppf<0x4E>(r1, r1);               // ^3
    float m0 = dppf<0x141>(r0, r0);        // half_mirror: ^7
    float m1 = dppf<0x141>(r1, r1);
    float m2 = dppf<0x141>(r2, r2);
    float m3 = dppf<0x141>(r3, r3);
    r4 = dppf<0x1B>(m0, m0);               // quad_perm(3,2,1,0): ^3 => net ^4
    r5 = dppf<0x1B>(m1, m1);               // ^5
    r6 = dppf<0x1B>(m2, m2);               // ^6
    r7 = dppf<0x1B>(m3, m3);               // ^7
  }
  if (gate == 0) {
    out[(size_t)SS * BB * HH + (size_t)b * HH + q] = h_own;                       // hx
    out[(size_t)SS * BB * HH + (size_t)BB * HH + (size_t)b * HH + q] = c_own;     // cx
  }
}

extern "C" void kernel_launch(void* const* d_in, const int* in_sizes, int n_in,
                              void* d_out, int out_size, void* d_ws, size_t ws_size,
                              hipStream_t stream) {
  const float* x   = (const float*)d_in[0];
  const float* cw  = (const float*)d_in[1];
  const float* lng = (const float*)d_in[2];
  const float* lnb = (const float*)d_in[3];
  const float* Wf_ = (const float*)d_in[4];
  const float* bf_ = (const float*)d_in[5];
  const float* Wi_ = (const float*)d_in[6];
  const float* bi_ = (const float*)d_in[7];
  const float* Wg_ = (const float*)d_in[8];
  const float* bg_ = (const float*)d_in[9];
  const float* Wo_ = (const float*)d_in[10];
  const float* bo_ = (const float*)d_in[11];
  float* out = (float*)d_out;
  float* wt  = (float*)d_ws;   // 3*128*8 floats = 12 KB

  kw_transpose<<<12, 256, 0, stream>>>(cw, wt);
  kconv<<<dim3(BB / 256, SS), 256, 0, stream>>>(x, wt, out);
  krec<<<BB / 2, 64, 0, stream>>>(lng, lnb, Wf_, bf_, Wi_, bi_, Wg_, bg_, Wo_, bo_, out);
}